// Round 8
// baseline (277.267 us; speedup 1.0000x reference)
//
#include <hip/hip_runtime.h>
#include <math.h>

constexpr int DIM = 64;
constexpr int S = 8;
constexpr int WPB = 4;                 // waves per block (256 threads)
constexpr int BLOCK = WPB * 64;
constexpr int GRID = 2048;             // 8 blocks/CU x 256 CU resident -> 8 iters/wave

constexpr int N_USER = 200000;
constexpr int N_ITEM = 100000;
constexpr size_t USR16_BYTES  = (size_t)N_USER * DIM * 2;   // 25,600,000
constexpr size_t ITEM16_BYTES = (size_t)N_ITEM * DIM * 2;   // 12,800,000
constexpr size_t WS_NEEDED    = USR16_BYTES + ITEM16_BYTES; // 38,400,000

typedef __attribute__((ext_vector_type(8))) __bf16 bf16x8;   // 4 VGPRs: MFMA A/B frag
typedef __attribute__((ext_vector_type(4))) float  f32x4;    // MFMA C/D frag
typedef __attribute__((ext_vector_type(8))) float     f32x8;
typedef __attribute__((ext_vector_type(8))) _Float16  f16x8;
typedef __attribute__((ext_vector_type(2))) _Float16  f16x2;

// pure-LDS fence: orders ds ops without draining vmcnt (keeps global gathers in flight)
#define LDS_FENCE() asm volatile("s_waitcnt lgkmcnt(0)" ::: "memory")
// scheduling pin: keep prefetch issue-points where the source puts them (anti-R2-sink)
#define SCHED_PIN() __builtin_amdgcn_sched_barrier(0)

// DPP quad-perm lane exchange (VALU pipe, not DS)
template <int CTRL>
__device__ __forceinline__ float dppx(float x) {
    return __builtin_bit_cast(float,
        __builtin_amdgcn_mov_dpp(__builtin_bit_cast(int, x), CTRL, 0xf, 0xf, true));
}
#define XOR1 0xB1   // quad_perm(1,0,3,2)
#define XOR2 0x4E   // quad_perm(2,3,0,1)

// pack two floats as bf16 (RNE-ish) into one dword: lo=a, hi=b
__device__ __forceinline__ unsigned pk_bf16(float a, float b) {
    unsigned ua = __builtin_bit_cast(unsigned, a);
    unsigned ub = __builtin_bit_cast(unsigned, b);
    ua = (ua + 0x8000u) >> 16;
    ub = (ub + 0x8000u) & 0xffff0000u;
    return ua | ub;
}

// softmax over the 8 scores held at lane&7; returns the 4 weights this lane's
// HALF consumes in pair layout: wt[t] = w[2t + half]  (4 bpermutes, not 8)
__device__ __forceinline__ void octet_softmax_pair(float sc, int half, float* wt) {
    float m = sc;
    m = fmaxf(m, dppx<XOR1>(m));
    m = fmaxf(m, dppx<XOR2>(m));
    m = fmaxf(m, __shfl_xor(m, 4));
    float e = __expf(sc - m);
    float s = e;
    s += dppx<XOR1>(s);
    s += dppx<XOR2>(s);
    s += __shfl_xor(s, 4);
    float w = e / s;
    #pragma unroll
    for (int t = 0; t < 4; t++) wt[t] = __shfl(w, 2 * t + half);   // lane 2t+half holds s=2t+half
}

// paired-row gather: this half-wave loads rows {2t+half}, t=0..3, dword dw
// (dims 2dw, 2dw+1). One wave instruction covers TWO rows (the R8 lever).
template <bool USE16>
__device__ __forceinline__ void pair_gather(
    const float* tbl32, const _Float16* tbl16,
    int4 i0, int4 i1, int half, int dw, uint2* pd)
{
    const int n0 = half ? i0.y : i0.x;
    const int n1 = half ? i0.w : i0.z;
    const int n2 = half ? i1.y : i1.x;
    const int n3 = half ? i1.w : i1.z;
    if constexpr (USE16) {
        pd[0].x = ((const unsigned*)(tbl16 + ((unsigned)n0 << 6)))[dw];
        pd[1].x = ((const unsigned*)(tbl16 + ((unsigned)n1 << 6)))[dw];
        pd[2].x = ((const unsigned*)(tbl16 + ((unsigned)n2 << 6)))[dw];
        pd[3].x = ((const unsigned*)(tbl16 + ((unsigned)n3 << 6)))[dw];
    } else {
        pd[0] = ((const uint2*)(tbl32 + ((unsigned)n0 << 6)))[dw];
        pd[1] = ((const uint2*)(tbl32 + ((unsigned)n1 << 6)))[dw];
        pd[2] = ((const uint2*)(tbl32 + ((unsigned)n2 << 6)))[dw];
        pd[3] = ((const uint2*)(tbl32 + ((unsigned)n3 << 6)))[dw];
    }
}

template <bool USE16>
__device__ __forceinline__ float2 unpk(uint2 p) {
    if constexpr (USE16) {
        const f16x2 h = __builtin_bit_cast(f16x2, p.x);
        return make_float2((float)h[0], (float)h[1]);
    } else {
        return make_float2(__builtin_bit_cast(float, p.x), __builtin_bit_cast(float, p.y));
    }
}

// accumulate this half's 4 rows into the (L,H) dim-pair accumulators
template <bool USE16>
__device__ __forceinline__ void pair_fma(const uint2* pd, const float* wt, float& aL, float& aH) {
    #pragma unroll
    for (int t = 0; t < 4; t++) {
        const float2 r = unpk<USE16>(pd[t]);
        aL = fmaf(wt[t], r.x, aL);
        aH = fmaf(wt[t], r.y, aH);
    }
}

// stage x (pair layout: lane holds dims 2dw,2dw+1) into LDS as bf16 hi + residual.
// Both halves write identical data to the same dwords — benign duplicate.
__device__ __forceinline__ void stage_x_pair(float xL, float xH, int dw, unsigned short* xw) {
    LDS_FENCE();                               // WAR: prior A-frag reads done before overwrite
    const unsigned bL  = __builtin_bit_cast(unsigned, xL);
    const unsigned hbL = (bL + 0x8000u) & 0xffff0000u;
    const unsigned bH  = __builtin_bit_cast(unsigned, xH);
    const unsigned hbH = (bH + 0x8000u) & 0xffff0000u;
    const float rL = xL - __builtin_bit_cast(float, hbL);
    const float rH = xH - __builtin_bit_cast(float, hbH);
    ((unsigned*)xw)[dw]      = (hbL >> 16) | hbH;     // shorts [2dw]=hi(xL), [2dw+1]=hi(xH)
    ((unsigned*)xw)[32 + dw] = pk_bf16(rL, rH);       // residuals
    LDS_FENCE();                               // RAW: writes visible to whole wave
}

// h = relu(x @ W + b) via MFMA 16x16x32 bf16 (x already staged in sX)
__device__ __forceinline__ void matvec_core(
    const bf16x8* xa00, const bf16x8* xa01,    // kt=0: hi, lo
    const bf16x8* xa10, const bf16x8* xa11,    // kt=1: hi, lo
    const unsigned* bf,                        // &sBF[lane*4]; + kt*1024 + nt*256
    float b0, float b1, float b2, float b3,
    float& h0, float& h1, float& h2, float& h3)
{
    f32x4 a0 = {0.f, 0.f, 0.f, 0.f};
    f32x4 a1 = a0, a2 = a0, a3 = a0;

    // K-tile 0 (k = 0..31)
    {
        const bf16x8 ah = *xa00, al = *xa01;
        const bf16x8 w0 = *(const bf16x8*)(bf);
        const bf16x8 w1 = *(const bf16x8*)(bf + 256);
        const bf16x8 w2 = *(const bf16x8*)(bf + 512);
        const bf16x8 w3 = *(const bf16x8*)(bf + 768);
        a0 = __builtin_amdgcn_mfma_f32_16x16x32_bf16(ah, w0, a0, 0, 0, 0);
        a0 = __builtin_amdgcn_mfma_f32_16x16x32_bf16(al, w0, a0, 0, 0, 0);
        a1 = __builtin_amdgcn_mfma_f32_16x16x32_bf16(ah, w1, a1, 0, 0, 0);
        a1 = __builtin_amdgcn_mfma_f32_16x16x32_bf16(al, w1, a1, 0, 0, 0);
        a2 = __builtin_amdgcn_mfma_f32_16x16x32_bf16(ah, w2, a2, 0, 0, 0);
        a2 = __builtin_amdgcn_mfma_f32_16x16x32_bf16(al, w2, a2, 0, 0, 0);
        a3 = __builtin_amdgcn_mfma_f32_16x16x32_bf16(ah, w3, a3, 0, 0, 0);
        a3 = __builtin_amdgcn_mfma_f32_16x16x32_bf16(al, w3, a3, 0, 0, 0);
    }
    // K-tile 1 (k = 32..63)
    {
        const bf16x8 ah = *xa10, al = *xa11;
        const bf16x8 w0 = *(const bf16x8*)(bf + 1024);
        const bf16x8 w1 = *(const bf16x8*)(bf + 1280);
        const bf16x8 w2 = *(const bf16x8*)(bf + 1536);
        const bf16x8 w3 = *(const bf16x8*)(bf + 1792);
        a0 = __builtin_amdgcn_mfma_f32_16x16x32_bf16(ah, w0, a0, 0, 0, 0);
        a0 = __builtin_amdgcn_mfma_f32_16x16x32_bf16(al, w0, a0, 0, 0, 0);
        a1 = __builtin_amdgcn_mfma_f32_16x16x32_bf16(ah, w1, a1, 0, 0, 0);
        a1 = __builtin_amdgcn_mfma_f32_16x16x32_bf16(al, w1, a1, 0, 0, 0);
        a2 = __builtin_amdgcn_mfma_f32_16x16x32_bf16(ah, w2, a2, 0, 0, 0);
        a2 = __builtin_amdgcn_mfma_f32_16x16x32_bf16(al, w2, a2, 0, 0, 0);
        a3 = __builtin_amdgcn_mfma_f32_16x16x32_bf16(ah, w3, a3, 0, 0, 0);
        a3 = __builtin_amdgcn_mfma_f32_16x16x32_bf16(al, w3, a3, 0, 0, 0);
    }

    h0 = fmaxf(a0[0] + b0, 0.f);
    h1 = fmaxf(a1[0] + b1, 0.f);
    h2 = fmaxf(a2[0] + b2, 0.f);
    h3 = fmaxf(a3[0] + b3, 0.f);
}

// fp32 -> fp16 table conversion: thread i converts 8 elements (32B read, 16B write).
__global__ __launch_bounds__(256)
void cvt16_kernel(const float* __restrict__ usr_feat, const float* __restrict__ item_feat,
                  _Float16* __restrict__ usr16, _Float16* __restrict__ item16,
                  int n8u, int n8t)
{
    const int i = blockIdx.x * 256 + threadIdx.x;
    if (i >= n8t) return;
    const float* src = (i < n8u) ? usr_feat : item_feat;
    _Float16*   dst = (i < n8u) ? usr16    : item16;
    const int j = (i < n8u) ? i : (i - n8u);
    const f32x8 v = ((const f32x8*)src)[j];
    ((f16x8*)dst)[j] = __builtin_convertvector(v, f16x8);   // RNE per element
}

template <bool USE16>
__global__ __launch_bounds__(BLOCK, 4)   // VGPR cap 128; actual ~64-80 -> 8 blocks/CU resident
void sestkgcn_kernel(
    const int*   __restrict__ u_idx,
    const int*   __restrict__ v_idx,
    const float* __restrict__ usr_feat,
    const float* __restrict__ item_feat,
    const float* __restrict__ rel_feat,
    const int*   __restrict__ neigh_uu,
    const float* __restrict__ neigh_uu_st,
    const int*   __restrict__ neigh_ui,
    const float* __restrict__ neigh_ui_rat,
    const float* __restrict__ neigh_ui_vot,
    const float* __restrict__ neigh_ui_tim,
    const int*   __restrict__ neigh_iu,
    const float* __restrict__ neigh_iu_rat,
    const float* __restrict__ neigh_iu_vot,
    const float* __restrict__ neigh_iu_tim,
    const int*   __restrict__ neigh_ii,
    const int*   __restrict__ neigh_ir,
    const float* __restrict__ Wu,
    const float* __restrict__ bu,
    const float* __restrict__ Wv,
    const float* __restrict__ bv,
    const _Float16* __restrict__ usr16,    // fp16 gather tables (USE16 only)
    const _Float16* __restrict__ item16,
    float*       __restrict__ out,
    int n)
{
    __shared__ unsigned sBFu[2048];
    __shared__ unsigned sBFv[2048];
    __shared__ __align__(16) unsigned short sX[WPB][128];

    const int tid = threadIdx.x;
    for (int i = tid; i < 2048; i += BLOCK) {
        const int d = i & 3, l = (i >> 2) & 63, f = i >> 8;
        const int row = ((f >> 2) << 5) + ((l >> 4) << 3) + (d << 1);
        const int col = ((f & 3) << 4) + (l & 15);
        sBFu[i] = pk_bf16(Wu[row * DIM + col], Wu[(row + 1) * DIM + col]);
        sBFv[i] = pk_bf16(Wv[row * DIM + col], Wv[(row + 1) * DIM + col]);
    }
    __syncthreads();

    const int wave = tid >> 6;
    const int lane = tid & 63;
    const int ls   = lane & 7;
    const int g    = lane >> 4;    // MFMA lanegroup
    const int c    = lane & 15;    // MFMA column within N-tile
    const int half = lane >> 5;    // row-pair parity this half-wave covers
    const int dw   = lane & 31;    // dword index = dim pair {2dw, 2dw+1}

    unsigned short* xw = &sX[wave][0];
    const bf16x8* xa00 = (const bf16x8*)&sX[wave][g * 8];        // kt0 hi
    const bf16x8* xa01 = (const bf16x8*)&sX[wave][64 + g * 8];   // kt0 lo
    const bf16x8* xa10 = (const bf16x8*)&sX[wave][32 + g * 8];   // kt1 hi
    const bf16x8* xa11 = (const bf16x8*)&sX[wave][96 + g * 8];   // kt1 lo
    const unsigned* bfu = &sBFu[lane * 4];
    const unsigned* bfv = &sBFv[lane * 4];

    const float bu0 = bu[c], bu1 = bu[c + 16], bu2 = bu[c + 32], bu3 = bu[c + 48];
    const float bv0 = bv[c], bv1 = bv[c + 16], bv2 = bv[c + 32], bv3 = bv[c + 48];

    const int stride = GRID * WPB;
    int b = blockIdx.x * WPB + wave;
    if (b >= n) return;

    // ================= prologue: fill pipeline for first query =================
    int u = u_idx[b], v = v_idx[b];
    int bc1 = b + stride; if (bc1 >= n) bc1 = b;
    int u1 = u_idx[bc1], v1 = v_idx[bc1];      // ids(b+1)

    unsigned u8 = (unsigned)u << 3, v8 = (unsigned)v << 3;
    // metadata(b)
    int4 iuu0 = ((const int4*)(neigh_uu + u8))[0];
    int4 iuu1 = ((const int4*)(neigh_uu + u8))[1];
    int4 iui0 = ((const int4*)(neigh_ui + u8))[0];
    int4 iui1 = ((const int4*)(neigh_ui + u8))[1];
    int4 iiu0 = ((const int4*)(neigh_iu + v8))[0];
    int4 iiu1 = ((const int4*)(neigh_iu + v8))[1];
    int4 iii0 = ((const int4*)(neigh_ii + v8))[0];
    int4 iii1 = ((const int4*)(neigh_ii + v8))[1];
    int4 iir0 = ((const int4*)(neigh_ir + v8))[0];
    int4 iir1 = ((const int4*)(neigh_ir + v8))[1];
    float suu_r = neigh_uu_st[u8 + ls];
    float uir = neigh_ui_rat[u8 + ls], uiv = neigh_ui_vot[u8 + ls], uit = neigh_ui_tim[u8 + ls];
    float iur = neigh_iu_rat[v8 + ls], ivv = neigh_iu_vot[v8 + ls], ivt = neigh_iu_tim[v8 + ls];
    float ud_c = usr_feat[((unsigned)u << 6) | (unsigned)lane];                       // lane=dim (KG att)
    float2 vd_c = ((const float2*)(item_feat + ((unsigned)v << 6)))[dw];              // pair layout
    // rows(b) — paired-row gathers: 16 wave-loads instead of 32
    uint2 pdu_uu[4], pdu_ui[4], pdi_iu[4], pdi_ii[4];
    pair_gather<USE16>(usr_feat,  usr16,  iuu0, iuu1, half, dw, pdu_uu);
    pair_gather<USE16>(item_feat, item16, iui0, iui1, half, dw, pdu_ui);
    pair_gather<USE16>(usr_feat,  usr16,  iiu0, iiu1, half, dw, pdi_iu);
    pair_gather<USE16>(item_feat, item16, iii0, iii1, half, dw, pdi_ii);
    float  ud_n = 0.f;
    float2 vd_n = make_float2(0.f, 0.f);

    while (true) {
        // ---- A: rel rows(b) [old iir, fp32, lane=dim]; then idx(b+1); ids(b+2) ----
        float rr[S];
        {
            const int nir[S] = {iir0.x, iir0.y, iir0.z, iir0.w, iir1.x, iir1.y, iir1.z, iir1.w};
            #pragma unroll
            for (int s = 0; s < S; s++) rr[s] = rel_feat[((unsigned)nir[s] << 6) | (unsigned)lane];
        }
        const unsigned u81 = (unsigned)u1 << 3, v81 = (unsigned)v1 << 3;
        iuu0 = ((const int4*)(neigh_uu + u81))[0];
        iuu1 = ((const int4*)(neigh_uu + u81))[1];
        iui0 = ((const int4*)(neigh_ui + u81))[0];
        iui1 = ((const int4*)(neigh_ui + u81))[1];
        iiu0 = ((const int4*)(neigh_iu + v81))[0];
        iiu1 = ((const int4*)(neigh_iu + v81))[1];
        iii0 = ((const int4*)(neigh_ii + v81))[0];
        iii1 = ((const int4*)(neigh_ii + v81))[1];
        iir0 = ((const int4*)(neigh_ir + v81))[0];
        iir1 = ((const int4*)(neigh_ir + v81))[1];
        int b2c = b + 2 * stride; if (b2c >= n) b2c = b;
        const int u2 = u_idx[b2c], v2 = v_idx[b2c];
        SCHED_PIN();   // loads above must issue HERE, not at their uses

        // ---- C/D: user softmaxes + pair aggs (consume rows(b), in flight ~1 iter) ----
        float wt[4];
        float sumL, sumH;
        {
            octet_softmax_pair(suu_r, half, wt);
            float aL = 0.f, aH = 0.f;
            pair_fma<USE16>(pdu_uu, wt, aL, aH);
            octet_softmax_pair(uir * uiv * uit, half, wt);
            pair_fma<USE16>(pdu_ui, wt, aL, aH);
            // combine halves: each half covered rows of its parity only
            sumL = aL + __shfl_xor(aL, 32);
            sumH = aH + __shfl_xor(aH, 32);
        }
        // u embed in pair layout (u stays lane=dim for the KG attention below)
        const float udL = __shfl(ud_c, 2 * dw);
        const float udH = __shfl(ud_c, 2 * dw + 1);

        // ---- E: stage x_u + matvec hu ----
        float hu0, hu1, hu2, hu3;
        stage_x_pair(udL + sumL, udH + sumH, dw, xw);
        matvec_core(xa00, xa01, xa10, xa11, bfu, bu0, bu1, bu2, bu3, hu0, hu1, hu2, hu3);

        // ---- G1: item-user pair agg ----
        float aL = 0.f, aH = 0.f;
        octet_softmax_pair(iur * ivv * ivt, half, wt);
        pair_fma<USE16>(pdi_iu, wt, aL, aH);

        // ---- G2: KG attention (ud_c · rel rows, fp32, lane=dim) + pair agg ii ----
        {
            float p[S];
            #pragma unroll
            for (int s = 0; s < S; s++) p[s] = ud_c * rr[s];

            float m1[4];
            #pragma unroll
            for (int i = 0; i < 4; i++) {
                float lo = (lane & 1) ? p[2 * i + 1] : p[2 * i];
                float hi = (lane & 1) ? p[2 * i]     : p[2 * i + 1];
                m1[i] = lo + dppx<XOR1>(hi);
            }
            float m2[2];
            #pragma unroll
            for (int i = 0; i < 2; i++) {
                float lo = (lane & 2) ? m1[2 * i + 1] : m1[2 * i];
                float hi = (lane & 2) ? m1[2 * i]     : m1[2 * i + 1];
                m2[i] = lo + dppx<XOR2>(hi);
            }
            float lo = (lane & 4) ? m2[1] : m2[0];
            float hi = (lane & 4) ? m2[0] : m2[1];
            float att = lo + __shfl_xor(hi, 4);
            att += __shfl_xor(att, 8);
            att += __shfl_xor(att, 16);
            att += __shfl_xor(att, 32);
            octet_softmax_pair(att, half, wt);
        }
        pair_fma<USE16>(pdi_ii, wt, aL, aH);
        sumL = aL + __shfl_xor(aL, 32);
        sumH = aH + __shfl_xor(aH, 32);

        // ---- F: prefetch (b+1): paired rows into the (now dead) pd arrays, scores, embeds ----
        pair_gather<USE16>(usr_feat,  usr16,  iuu0, iuu1, half, dw, pdu_uu);
        pair_gather<USE16>(item_feat, item16, iui0, iui1, half, dw, pdu_ui);
        pair_gather<USE16>(usr_feat,  usr16,  iiu0, iiu1, half, dw, pdi_iu);
        pair_gather<USE16>(item_feat, item16, iii0, iii1, half, dw, pdi_ii);
        suu_r = neigh_uu_st[u81 + ls];
        uir = neigh_ui_rat[u81 + ls]; uiv = neigh_ui_vot[u81 + ls]; uit = neigh_ui_tim[u81 + ls];
        iur = neigh_iu_rat[v81 + ls]; ivv = neigh_iu_vot[v81 + ls]; ivt = neigh_iu_tim[v81 + ls];
        ud_n = usr_feat[((unsigned)u1 << 6) | (unsigned)lane];
        vd_n = ((const float2*)(item_feat + ((unsigned)v1 << 6)))[dw];
        SCHED_PIN();   // rows(b+1) must be in flight before the hv matvec below

        // ---- H: stage x_v + matvec hv + epilogue ----
        float hv0, hv1, hv2, hv3;
        stage_x_pair(vd_c.x + sumL, vd_c.y + sumH, dw, xw);
        matvec_core(xa00, xa01, xa10, xa11, bfv, bv0, bv1, bv2, bv3, hv0, hv1, hv2, hv3);

        float p = hu0 * hv0 + hu1 * hv1 + hu2 * hv2 + hu3 * hv3;
        p += dppx<XOR1>(p);
        p += dppx<XOR2>(p);
        p += __shfl_xor(p, 4);
        p += __shfl_xor(p, 8);
        if (lane == 0) out[b] = 5.0f / (1.0f + __expf(-p));

        // ---- rotate pipeline state ----
        b += stride;
        if (b >= n) break;
        u = u1; v = v1; u1 = u2; v1 = v2;
        ud_c = ud_n; vd_c = vd_n;
    }
}

extern "C" void kernel_launch(void* const* d_in, const int* in_sizes, int n_in,
                              void* d_out, int out_size, void* d_ws, size_t ws_size,
                              hipStream_t stream) {
    const int*   u_idx        = (const int*)  d_in[0];
    const int*   v_idx        = (const int*)  d_in[1];
    const float* usr_feat     = (const float*)d_in[2];
    const float* item_feat    = (const float*)d_in[3];
    const float* rel_feat     = (const float*)d_in[4];
    const int*   neigh_uu     = (const int*)  d_in[5];
    const float* neigh_uu_st  = (const float*)d_in[6];
    const int*   neigh_ui     = (const int*)  d_in[7];
    const float* neigh_ui_rat = (const float*)d_in[8];
    const float* neigh_ui_vot = (const float*)d_in[9];
    const float* neigh_ui_tim = (const float*)d_in[10];
    const int*   neigh_iu     = (const int*)  d_in[11];
    const float* neigh_iu_rat = (const float*)d_in[12];
    const float* neigh_iu_vot = (const float*)d_in[13];
    const float* neigh_iu_tim = (const float*)d_in[14];
    const int*   neigh_ii     = (const int*)  d_in[15];
    const int*   neigh_ir     = (const int*)  d_in[16];
    const float* Wu           = (const float*)d_in[17];
    const float* bu           = (const float*)d_in[18];
    const float* Wv           = (const float*)d_in[19];
    const float* bv           = (const float*)d_in[20];
    float*       out          = (float*)d_out;

    const int n = in_sizes[0];
    int blocks = (n + WPB - 1) / WPB;
    if (blocks > GRID) blocks = GRID;

    const bool use16 = (d_ws != nullptr) && (ws_size >= WS_NEEDED);
    if (use16) {
        _Float16* usr16  = (_Float16*)d_ws;
        _Float16* item16 = (_Float16*)((char*)d_ws + USR16_BYTES);
        const int n8u = N_USER * DIM / 8;          // 1.6M vectors
        const int n8t = n8u + N_ITEM * DIM / 8;    // 2.4M total
        cvt16_kernel<<<(n8t + 255) / 256, 256, 0, stream>>>(
            usr_feat, item_feat, usr16, item16, n8u, n8t);
        sestkgcn_kernel<true><<<blocks, BLOCK, 0, stream>>>(
            u_idx, v_idx, usr_feat, item_feat, rel_feat,
            neigh_uu, neigh_uu_st, neigh_ui, neigh_ui_rat, neigh_ui_vot, neigh_ui_tim,
            neigh_iu, neigh_iu_rat, neigh_iu_vot, neigh_iu_tim, neigh_ii, neigh_ir,
            Wu, bu, Wv, bv, usr16, item16, out, n);
    } else {
        sestkgcn_kernel<false><<<blocks, BLOCK, 0, stream>>>(
            u_idx, v_idx, usr_feat, item_feat, rel_feat,
            neigh_uu, neigh_uu_st, neigh_ui, neigh_ui_rat, neigh_ui_vot, neigh_ui_tim,
            neigh_iu, neigh_iu_rat, neigh_iu_vot, neigh_iu_tim, neigh_ii, neigh_ir,
            Wu, bu, Wv, bv, nullptr, nullptr, out, n);
    }
}

// Round 9
// 246.168 us; speedup vs baseline: 1.1263x; 1.1263x over previous
//
#include <hip/hip_runtime.h>
#include <math.h>

constexpr int DIM = 64;
constexpr int S = 8;
constexpr int WPB = 16;                // waves per block (1024 threads) — headline-best config (R1)
constexpr int BLOCK = WPB * 64;
constexpr int GRID = 512;              // 2 blocks/CU x 256 CU = 32 waves/CU; grid-stride over batch

typedef __attribute__((ext_vector_type(8))) __bf16 bf16x8;   // 4 VGPRs: MFMA A/B frag
typedef __attribute__((ext_vector_type(4))) float  f32x4;    // MFMA C/D frag

// pure-LDS fence: orders ds ops without draining vmcnt (keeps gathers in flight)
#define LDS_FENCE() asm volatile("s_waitcnt lgkmcnt(0)" ::: "memory")

// DPP quad-perm lane exchange (VALU pipe, not DS)
template <int CTRL>
__device__ __forceinline__ float dppx(float x) {
    return __builtin_bit_cast(float,
        __builtin_amdgcn_mov_dpp(__builtin_bit_cast(int, x), CTRL, 0xf, 0xf, true));
}
#define XOR1 0xB1   // quad_perm(1,0,3,2)
#define XOR2 0x4E   // quad_perm(2,3,0,1)

// pack two floats as bf16 (RNE-ish) into one dword: lo=a, hi=b
__device__ __forceinline__ unsigned pk_bf16(float a, float b) {
    unsigned ua = __builtin_bit_cast(unsigned, a);
    unsigned ub = __builtin_bit_cast(unsigned, b);
    ua = (ua + 0x8000u) >> 16;
    ub = (ub + 0x8000u) & 0xffff0000u;
    return ua | ub;
}

// 8-way softmax over lanes' (lane&7) scores; broadcasts w[0..7] to all lanes.
__device__ __forceinline__ void octet_softmax(float sc, float* wout) {
    float m = sc;
    m = fmaxf(m, dppx<XOR1>(m));
    m = fmaxf(m, dppx<XOR2>(m));
    m = fmaxf(m, __shfl_xor(m, 4));
    float e = __expf(sc - m);
    float s = e;
    s += dppx<XOR1>(s);
    s += dppx<XOR2>(s);
    s += __shfl_xor(s, 4);
    float w = e / s;
    #pragma unroll
    for (int k = 0; k < 8; k++) wout[k] = __shfl(w, k);   // lane k (mod 8) holds s=k
}

// h = relu(x @ W + b) via MFMA 16x16x32 bf16 (x split into bf16 hi + bf16 residual,
// broadcast to all 16 A-rows via per-lanegroup LDS read; W pre-staged in B-frag layout).
// setprio(1) around the MFMA cluster: waves here are phase-independent, so the CU
// scheduler favoring the compute-phase wave shortens the LDS->MFMA critical section
// (T5 mechanism — applicable because there is no barrier lockstep in this kernel).
__device__ __forceinline__ void matvec_h(
    float xv, int lane, unsigned short* xw,
    const bf16x8* xa00, const bf16x8* xa01,    // kt=0: hi, lo
    const bf16x8* xa10, const bf16x8* xa11,    // kt=1: hi, lo
    const unsigned* bf,                        // &sBF[lane*4]; + kt*1024 + nt*256
    float b0, float b1, float b2, float b3,
    float& h0, float& h1, float& h2, float& h3)
{
    LDS_FENCE();                               // WAR: prior A-frag reads done before overwrite
    const unsigned xb = __builtin_bit_cast(unsigned, xv);
    const unsigned hb = (xb + 0x8000u) & 0xffff0000u;
    const float xl = xv - __builtin_bit_cast(float, hb);
    xw[lane]      = (unsigned short)(hb >> 16);
    xw[64 + lane] = (unsigned short)((__builtin_bit_cast(unsigned, xl) + 0x8000u) >> 16);
    LDS_FENCE();                               // RAW: writes visible to whole wave

    f32x4 a0 = {0.f, 0.f, 0.f, 0.f};
    f32x4 a1 = a0, a2 = a0, a3 = a0;

    __builtin_amdgcn_s_setprio(1);
    // K-tile 0 (k = 0..31)
    {
        const bf16x8 ah = *xa00, al = *xa01;
        const bf16x8 w0 = *(const bf16x8*)(bf);
        const bf16x8 w1 = *(const bf16x8*)(bf + 256);
        const bf16x8 w2 = *(const bf16x8*)(bf + 512);
        const bf16x8 w3 = *(const bf16x8*)(bf + 768);
        a0 = __builtin_amdgcn_mfma_f32_16x16x32_bf16(ah, w0, a0, 0, 0, 0);
        a0 = __builtin_amdgcn_mfma_f32_16x16x32_bf16(al, w0, a0, 0, 0, 0);
        a1 = __builtin_amdgcn_mfma_f32_16x16x32_bf16(ah, w1, a1, 0, 0, 0);
        a1 = __builtin_amdgcn_mfma_f32_16x16x32_bf16(al, w1, a1, 0, 0, 0);
        a2 = __builtin_amdgcn_mfma_f32_16x16x32_bf16(ah, w2, a2, 0, 0, 0);
        a2 = __builtin_amdgcn_mfma_f32_16x16x32_bf16(al, w2, a2, 0, 0, 0);
        a3 = __builtin_amdgcn_mfma_f32_16x16x32_bf16(ah, w3, a3, 0, 0, 0);
        a3 = __builtin_amdgcn_mfma_f32_16x16x32_bf16(al, w3, a3, 0, 0, 0);
    }
    // K-tile 1 (k = 32..63)
    {
        const bf16x8 ah = *xa10, al = *xa11;
        const bf16x8 w0 = *(const bf16x8*)(bf + 1024);
        const bf16x8 w1 = *(const bf16x8*)(bf + 1280);
        const bf16x8 w2 = *(const bf16x8*)(bf + 1536);
        const bf16x8 w3 = *(const bf16x8*)(bf + 1792);
        a0 = __builtin_amdgcn_mfma_f32_16x16x32_bf16(ah, w0, a0, 0, 0, 0);
        a0 = __builtin_amdgcn_mfma_f32_16x16x32_bf16(al, w0, a0, 0, 0, 0);
        a1 = __builtin_amdgcn_mfma_f32_16x16x32_bf16(ah, w1, a1, 0, 0, 0);
        a1 = __builtin_amdgcn_mfma_f32_16x16x32_bf16(al, w1, a1, 0, 0, 0);
        a2 = __builtin_amdgcn_mfma_f32_16x16x32_bf16(ah, w2, a2, 0, 0, 0);
        a2 = __builtin_amdgcn_mfma_f32_16x16x32_bf16(al, w2, a2, 0, 0, 0);
        a3 = __builtin_amdgcn_mfma_f32_16x16x32_bf16(ah, w3, a3, 0, 0, 0);
        a3 = __builtin_amdgcn_mfma_f32_16x16x32_bf16(al, w3, a3, 0, 0, 0);
    }
    __builtin_amdgcn_s_setprio(0);

    // all 16 C rows equal (A rows replicated) -> reg 0 of each N-tile is h[16*nt + (lane&15)]
    h0 = fmaxf(a0[0] + b0, 0.f);
    h1 = fmaxf(a1[0] + b1, 0.f);
    h2 = fmaxf(a2[0] + b2, 0.f);
    h3 = fmaxf(a3[0] + b3, 0.f);
}

__global__ __launch_bounds__(BLOCK)
void sestkgcn_kernel(
    const int*   __restrict__ u_idx,
    const int*   __restrict__ v_idx,
    const float* __restrict__ usr_feat,
    const float* __restrict__ item_feat,
    const float* __restrict__ rel_feat,
    const int*   __restrict__ neigh_uu,
    const float* __restrict__ neigh_uu_st,
    const int*   __restrict__ neigh_ui,
    const float* __restrict__ neigh_ui_rat,
    const float* __restrict__ neigh_ui_vot,
    const float* __restrict__ neigh_ui_tim,
    const int*   __restrict__ neigh_iu,
    const float* __restrict__ neigh_iu_rat,
    const float* __restrict__ neigh_iu_vot,
    const float* __restrict__ neigh_iu_tim,
    const int*   __restrict__ neigh_ii,
    const int*   __restrict__ neigh_ir,
    const float* __restrict__ Wu,
    const float* __restrict__ bu,
    const float* __restrict__ Wv,
    const float* __restrict__ bv,
    float*       __restrict__ out,
    int n)
{
    // B-fragment layout for mfma_f32_16x16x32_bf16, frag f = kt*4+nt:
    //   sBF[(f*64 + lane)*4 + d] packs W[32*kt + 8*(lane>>4) + 2d][16*nt + (lane&15)] (lo)
    //   and row+1 (hi) — element j of the lane's 8 bf16 is k = 32*kt + 8*(lane>>4) + j.
    __shared__ unsigned sBFu[2048];
    __shared__ unsigned sBFv[2048];
    // per-wave x: shorts [0..63] = bf16 hi(x[k]), [64..127] = bf16 residual lo(x[k])
    __shared__ __align__(16) unsigned short sX[WPB][128];

    const int tid = threadIdx.x;
    for (int i = tid; i < 2048; i += BLOCK) {
        const int d = i & 3, l = (i >> 2) & 63, f = i >> 8;
        const int row = ((f >> 2) << 5) + ((l >> 4) << 3) + (d << 1);
        const int col = ((f & 3) << 4) + (l & 15);
        sBFu[i] = pk_bf16(Wu[row * DIM + col], Wu[(row + 1) * DIM + col]);
        sBFv[i] = pk_bf16(Wv[row * DIM + col], Wv[(row + 1) * DIM + col]);
    }
    if (tid < DIM) { /* bias staged via direct loads below; keep parity with R1 */ }
    __syncthreads();

    const int wave = tid >> 6;
    const int lane = tid & 63;
    const int ls   = lane & 7;
    const int g    = lane >> 4;    // MFMA lanegroup
    const int c    = lane & 15;    // MFMA column within N-tile

    unsigned short* xw = &sX[wave][0];
    const bf16x8* xa00 = (const bf16x8*)&sX[wave][g * 8];        // kt0 hi
    const bf16x8* xa01 = (const bf16x8*)&sX[wave][64 + g * 8];   // kt0 lo
    const bf16x8* xa10 = (const bf16x8*)&sX[wave][32 + g * 8];   // kt1 hi
    const bf16x8* xa11 = (const bf16x8*)&sX[wave][96 + g * 8];   // kt1 lo
    const unsigned* bfu = &sBFu[lane * 4];
    const unsigned* bfv = &sBFv[lane * 4];

    // bias in C-frag layout: lane (any group) needs dims {c, 16+c, 32+c, 48+c}
    const float bu0 = bu[c], bu1 = bu[c + 16], bu2 = bu[c + 32], bu3 = bu[c + 48];
    const float bv0 = bv[c], bv1 = bv[c + 16], bv2 = bv[c + 32], bv3 = bv[c + 48];

    const int stride = GRID * WPB;
    int b = blockIdx.x * WPB + wave;
    if (b >= n) return;

    int u = u_idx[b];
    int v = v_idx[b];

    while (b < n) {
        const int b2 = b + stride;
        const int bc = (b2 < n) ? b2 : b;
        const int u_nxt = u_idx[bc];
        const int v_nxt = v_idx[bc];

        const unsigned u8 = (unsigned)u << 3, v8 = (unsigned)v << 3;

        const float u_d = usr_feat[((unsigned)u << 6) | (unsigned)lane];
        const float v_d = item_feat[((unsigned)v << 6) | (unsigned)lane];

        const float sc_uu = neigh_uu_st[u8 + ls];
        const float sc_ui = neigh_ui_rat[u8 + ls] * neigh_ui_vot[u8 + ls] * neigh_ui_tim[u8 + ls];
        const float sc_iu = neigh_iu_rat[v8 + ls] * neigh_iu_vot[v8 + ls] * neigh_iu_tim[v8 + ls];

        // ---------------- user side ----------------
        float w[S];
        octet_softmax(sc_uu, w);
        float agg_uu = 0.f;
        {
            const int4 i0 = ((const int4*)(neigh_uu + u8))[0];
            const int4 i1 = ((const int4*)(neigh_uu + u8))[1];
            const int ni[S] = {i0.x, i0.y, i0.z, i0.w, i1.x, i1.y, i1.z, i1.w};
            float r[S];
            #pragma unroll
            for (int s = 0; s < S; s++) r[s] = usr_feat[((unsigned)ni[s] << 6) | (unsigned)lane];
            #pragma unroll
            for (int s = 0; s < S; s++) agg_uu = fmaf(w[s], r[s], agg_uu);
        }

        octet_softmax(sc_ui, w);
        float agg_ui = 0.f;
        {
            const int4 i0 = ((const int4*)(neigh_ui + u8))[0];
            const int4 i1 = ((const int4*)(neigh_ui + u8))[1];
            const int ni[S] = {i0.x, i0.y, i0.z, i0.w, i1.x, i1.y, i1.z, i1.w};
            float r[S];
            #pragma unroll
            for (int s = 0; s < S; s++) r[s] = item_feat[((unsigned)ni[s] << 6) | (unsigned)lane];
            #pragma unroll
            for (int s = 0; s < S; s++) agg_ui = fmaf(w[s], r[s], agg_ui);
        }

        // user_h = relu(x @ Wu + bu) via MFMA
        float hu0, hu1, hu2, hu3;
        matvec_h(u_d + agg_uu + agg_ui, lane, xw, xa00, xa01, xa10, xa11,
                 bfu, bu0, bu1, bu2, bu3, hu0, hu1, hu2, hu3);

        // ---------------- item side ----------------
        octet_softmax(sc_iu, w);
        float agg_iu = 0.f;
        {
            const int4 i0 = ((const int4*)(neigh_iu + v8))[0];
            const int4 i1 = ((const int4*)(neigh_iu + v8))[1];
            const int ni[S] = {i0.x, i0.y, i0.z, i0.w, i1.x, i1.y, i1.z, i1.w};
            float r[S];
            #pragma unroll
            for (int s = 0; s < S; s++) r[s] = usr_feat[((unsigned)ni[s] << 6) | (unsigned)lane];
            #pragma unroll
            for (int s = 0; s < S; s++) agg_iu = fmaf(w[s], r[s], agg_iu);
        }

        // KG attention: merge 8 dot-products so lane holds total for s=lane&7
        {
            const int4 r0 = ((const int4*)(neigh_ir + v8))[0];
            const int4 r1 = ((const int4*)(neigh_ir + v8))[1];
            const int nr[S] = {r0.x, r0.y, r0.z, r0.w, r1.x, r1.y, r1.z, r1.w};
            float p[S];
            #pragma unroll
            for (int s = 0; s < S; s++) p[s] = u_d * rel_feat[((unsigned)nr[s] << 6) | (unsigned)lane];

            float m1[4];
            #pragma unroll
            for (int i = 0; i < 4; i++) {
                float lo = (lane & 1) ? p[2 * i + 1] : p[2 * i];
                float hi = (lane & 1) ? p[2 * i]     : p[2 * i + 1];
                m1[i] = lo + dppx<XOR1>(hi);
            }
            float m2[2];
            #pragma unroll
            for (int i = 0; i < 2; i++) {
                float lo = (lane & 2) ? m1[2 * i + 1] : m1[2 * i];
                float hi = (lane & 2) ? m1[2 * i]     : m1[2 * i + 1];
                m2[i] = lo + dppx<XOR2>(hi);
            }
            float lo = (lane & 4) ? m2[1] : m2[0];
            float hi = (lane & 4) ? m2[0] : m2[1];
            float att = lo + __shfl_xor(hi, 4);
            att += __shfl_xor(att, 8);
            att += __shfl_xor(att, 16);
            att += __shfl_xor(att, 32);
            octet_softmax(att, w);
        }
        float agg_ii = 0.f;
        {
            const int4 i0 = ((const int4*)(neigh_ii + v8))[0];
            const int4 i1 = ((const int4*)(neigh_ii + v8))[1];
            const int ni[S] = {i0.x, i0.y, i0.z, i0.w, i1.x, i1.y, i1.z, i1.w};
            float r[S];
            #pragma unroll
            for (int s = 0; s < S; s++) r[s] = item_feat[((unsigned)ni[s] << 6) | (unsigned)lane];
            #pragma unroll
            for (int s = 0; s < S; s++) agg_ii = fmaf(w[s], r[s], agg_ii);
        }

        // item_h = relu(x @ Wv + bv) via MFMA
        float hv0, hv1, hv2, hv3;
        matvec_h(v_d + agg_iu + agg_ii, lane, xw, xa00, xa01, xa10, xa11,
                 bfv, bv0, bv1, bv2, bv3, hv0, hv1, hv2, hv3);

        // score = sigmoid(dot(user_h, item_h)) * 5 — h lives in C-frag layout:
        // lane holds dims {c, 16+c, 32+c, 48+c}; reduce over the 16 columns.
        float p = hu0 * hv0 + hu1 * hv1 + hu2 * hv2 + hu3 * hv3;
        p += dppx<XOR1>(p);
        p += dppx<XOR2>(p);
        p += __shfl_xor(p, 4);
        p += __shfl_xor(p, 8);
        if (lane == 0) out[b] = 5.0f / (1.0f + __expf(-p));

        b = b2;
        u = u_nxt;
        v = v_nxt;
    }
}

extern "C" void kernel_launch(void* const* d_in, const int* in_sizes, int n_in,
                              void* d_out, int out_size, void* d_ws, size_t ws_size,
                              hipStream_t stream) {
    const int*   u_idx        = (const int*)  d_in[0];
    const int*   v_idx        = (const int*)  d_in[1];
    const float* usr_feat     = (const float*)d_in[2];
    const float* item_feat    = (const float*)d_in[3];
    const float* rel_feat     = (const float*)d_in[4];
    const int*   neigh_uu     = (const int*)  d_in[5];
    const float* neigh_uu_st  = (const float*)d_in[6];
    const int*   neigh_ui     = (const int*)  d_in[7];
    const float* neigh_ui_rat = (const float*)d_in[8];
    const float* neigh_ui_vot = (const float*)d_in[9];
    const float* neigh_ui_tim = (const float*)d_in[10];
    const int*   neigh_iu     = (const int*)  d_in[11];
    const float* neigh_iu_rat = (const float*)d_in[12];
    const float* neigh_iu_vot = (const float*)d_in[13];
    const float* neigh_iu_tim = (const float*)d_in[14];
    const int*   neigh_ii     = (const int*)  d_in[15];
    const int*   neigh_ir     = (const int*)  d_in[16];
    const float* Wu           = (const float*)d_in[17];
    const float* bu           = (const float*)d_in[18];
    const float* Wv           = (const float*)d_in[19];
    const float* bv           = (const float*)d_in[20];
    float*       out          = (float*)d_out;

    const int n = in_sizes[0];
    int blocks = (n + WPB - 1) / WPB;
    if (blocks > GRID) blocks = GRID;
    sestkgcn_kernel<<<blocks, BLOCK, 0, stream>>>(
        u_idx, v_idx, usr_feat, item_feat, rel_feat,
        neigh_uu, neigh_uu_st, neigh_ui, neigh_ui_rat, neigh_ui_vot, neigh_ui_tim,
        neigh_iu, neigh_iu_rat, neigh_iu_vot, neigh_iu_tim, neigh_ii, neigh_ir,
        Wu, bu, Wv, bv, out, n);
}